// Round 1
// baseline (329.127 us; speedup 1.0000x reference)
//
#include <hip/hip_runtime.h>
#include <hip/hip_bf16.h>

typedef __attribute__((ext_vector_type(4))) float  f32x4;
typedef __attribute__((ext_vector_type(8))) __bf16 bf16x8;
typedef __attribute__((ext_vector_type(4))) __bf16 bf16x4;

#define LOG2E_O16 0.09016844005556021f  // log2(e)/16  (scale = 1/sqrt(256))

// ---------------- X = GA[g,n] * rep_R, fp32 -> bf16 ----------------
__global__ __launch_bounds__(256) void scale_kernel(
    const float* __restrict__ rep, const float* __restrict__ GA, __bf16* __restrict__ X)
{
  size_t i = (size_t)blockIdx.x * 256 + threadIdx.x;   // 2097152 threads, 4 elems each
  size_t e = i * 4;
  f32x4 r = *(const f32x4*)(rep + e);
  int dn = (int)(e >> 8);          // (b*16+g)*512 + n
  int n  = dn & 511;
  int g  = (dn >> 9) & 15;
  float ga = GA[g * 512 + n];
  bf16x4 o;
  o[0] = (__bf16)(r[0] * ga); o[1] = (__bf16)(r[1] * ga);
  o[2] = (__bf16)(r[2] * ga); o[3] = (__bf16)(r[3] * ga);
  *(bf16x4*)(X + e) = o;
}

// ---------------- generic MFMA GEMM: C = epi(A(bf16) @ B(f32->bf16) + bias) ----------------
// EPI: 0 none, 1 relu, 2 R + relu(acc)   OUTF32: write float instead of bf16
// M % 64 == 0, N % 64 == 0, K % 32 == 0
template<int EPI, bool OUTF32>
__global__ __launch_bounds__(256) void gemm_kernel(
    const __bf16* __restrict__ A, const float* __restrict__ B,
    const float* __restrict__ bias, const __bf16* __restrict__ R,
    void* __restrict__ Cv, int M, int N, int K)
{
  __shared__ __bf16 sA[64][40];   // [row][k], +8 pad
  __shared__ __bf16 sB[64][40];   // [col][k] (transposed), +8 pad
  const int tid  = threadIdx.x;
  const int lane = tid & 63;
  const int wv   = tid >> 6;
  const int wr   = (wv >> 1) * 32;
  const int wc   = (wv & 1) * 32;
  const int bm   = blockIdx.x * 64;
  const int bn   = blockIdx.y * 64;
  const int l16  = lane & 15;
  const int lk8  = (lane >> 4) * 8;

  const int a_r = tid >> 2, a_c = (tid & 3) * 8;   // A stage: 64 rows x 32 k
  const int b_c = tid & 63, b_k = (tid >> 6) * 8;  // B stage: 64 cols x 32 k

  f32x4 acc[2][2] = {};

  for (int k0 = 0; k0 < K; k0 += 32) {
    bf16x8 av = *(const bf16x8*)(A + (size_t)(bm + a_r) * K + k0 + a_c);
    float bvf[8];
#pragma unroll
    for (int j = 0; j < 8; ++j)
      bvf[j] = B[(size_t)(k0 + b_k + j) * N + bn + b_c];   // coalesced over lanes
    *(bf16x8*)&sA[a_r][a_c] = av;
    bf16x8 bb;
#pragma unroll
    for (int j = 0; j < 8; ++j) bb[j] = (__bf16)bvf[j];
    *(bf16x8*)&sB[b_c][b_k] = bb;
    __syncthreads();
    bf16x8 af0 = *(const bf16x8*)&sA[wr + l16][lk8];
    bf16x8 af1 = *(const bf16x8*)&sA[wr + 16 + l16][lk8];
    bf16x8 bf0 = *(const bf16x8*)&sB[wc + l16][lk8];
    bf16x8 bf1 = *(const bf16x8*)&sB[wc + 16 + l16][lk8];
    acc[0][0] = __builtin_amdgcn_mfma_f32_16x16x32_bf16(af0, bf0, acc[0][0], 0, 0, 0);
    acc[0][1] = __builtin_amdgcn_mfma_f32_16x16x32_bf16(af0, bf1, acc[0][1], 0, 0, 0);
    acc[1][0] = __builtin_amdgcn_mfma_f32_16x16x32_bf16(af1, bf0, acc[1][0], 0, 0, 0);
    acc[1][1] = __builtin_amdgcn_mfma_f32_16x16x32_bf16(af1, bf1, acc[1][1], 0, 0, 0);
    __syncthreads();
  }

#pragma unroll
  for (int mi = 0; mi < 2; ++mi)
#pragma unroll
    for (int ni = 0; ni < 2; ++ni) {
      int col = bn + wc + ni * 16 + l16;
      float bval = bias[col];
      int row0 = bm + wr + mi * 16 + (lane >> 4) * 4;
#pragma unroll
      for (int i = 0; i < 4; ++i) {
        int row = row0 + i;
        float v = acc[mi][ni][i] + bval;
        if (EPI == 1) v = fmaxf(v, 0.f);
        if (EPI == 2) v = (float)R[(size_t)row * N + col] + fmaxf(v, 0.f);
        if (OUTF32) ((float*)Cv)[(size_t)row * N + col] = v;
        else        ((__bf16*)Cv)[(size_t)row * N + col] = (__bf16)v;
      }
    }
}

// ---------------- fused SAB attention, one block per (head, item) ----------------
// O = q + softmax(q k^T / 16) v, per head slice of 64 channels; in-place over Q.
__global__ __launch_bounds__(512) void attn_sab_kernel(
    __bf16* __restrict__ Q, const __bf16* __restrict__ Kb, const __bf16* __restrict__ Vb)
{
  __shared__ __bf16 sK[512][72];      // [key][d]  (+8 pad: stride 144B -> conflict-free)
  __shared__ __bf16 sV[64][520];      // [d][key]  transposed (+8 pad)
  __shared__ __bf16 sP[8][16][72];    // per-wave P staging (D-layout -> A-layout bridge)

  const int head = blockIdx.x;
  const int item = blockIdx.y;
  const int tid  = threadIdx.x;
  const int lane = tid & 63;
  const int wv   = tid >> 6;
  const int l16  = lane & 15;
  const int lg   = lane >> 4;                     // 0..3
  const size_t base = (size_t)item * (512 * 256) + (size_t)head * 64;

  {
    const int kr = tid >> 3, kc8 = (tid & 7) * 8;     // K: 64 rows x 64 ch per pass
    const int vch = tid & 63, vk8 = (tid >> 6) * 8;   // V: 64 ch x 64 keys per pass
#pragma unroll
    for (int pass = 0; pass < 8; ++pass) {
      int row = pass * 64 + kr;
      *(bf16x8*)&sK[row][kc8] = *(const bf16x8*)(Kb + base + (size_t)row * 256 + kc8);
      int key0 = pass * 64 + vk8;
      bf16x8 vvv;
#pragma unroll
      for (int j = 0; j < 8; ++j)
        vvv[j] = Vb[base + (size_t)(key0 + j) * 256 + vch];
      *(bf16x8*)&sV[vch][key0] = vvv;
    }
  }
  __syncthreads();

  for (int qb = 0; qb < 4; ++qb) {
    const int qrow0 = wv * 64 + qb * 16;
    const size_t qbase = base + (size_t)(qrow0 + l16) * 256;
    bf16x8 aq0 = *(const bf16x8*)(Q + qbase + lg * 8);        // k 0..31
    bf16x8 aq1 = *(const bf16x8*)(Q + qbase + 32 + lg * 8);   // k 32..63
    f32x4 acco[4] = {};
    float lsum[4] = {0.f, 0.f, 0.f, 0.f};

    for (int kc = 0; kc < 512; kc += 64) {
#pragma unroll
      for (int st = 0; st < 4; ++st) {
        const int krow = kc + st * 16 + l16;
        f32x4 s = {};
        s = __builtin_amdgcn_mfma_f32_16x16x32_bf16(aq0, *(const bf16x8*)&sK[krow][lg * 8], s, 0, 0, 0);
        s = __builtin_amdgcn_mfma_f32_16x16x32_bf16(aq1, *(const bf16x8*)&sK[krow][32 + lg * 8], s, 0, 0, 0);
#pragma unroll
        for (int i = 0; i < 4; ++i) {
          float p = exp2f(s[i] * LOG2E_O16);   // logits tiny: no max-subtract needed
          lsum[i] += p;
          sP[wv][lg * 4 + i][st * 16 + l16] = (__bf16)p;
        }
      }
#pragma unroll
      for (int kk = 0; kk < 2; ++kk) {
        bf16x8 ap = *(const bf16x8*)&sP[wv][l16][kk * 32 + lg * 8];
#pragma unroll
        for (int vt = 0; vt < 4; ++vt) {
          bf16x8 bvv = *(const bf16x8*)&sV[vt * 16 + l16][kc + kk * 32 + lg * 8];
          acco[vt] = __builtin_amdgcn_mfma_f32_16x16x32_bf16(ap, bvv, acco[vt], 0, 0, 0);
        }
      }
    }
#pragma unroll
    for (int m = 1; m < 16; m <<= 1)
#pragma unroll
      for (int i = 0; i < 4; ++i) lsum[i] += __shfl_xor(lsum[i], m, 64);

#pragma unroll
    for (int vt = 0; vt < 4; ++vt)
#pragma unroll
      for (int i = 0; i < 4; ++i) {
        int row = qrow0 + lg * 4 + i;
        size_t idx = base + (size_t)row * 256 + vt * 16 + l16;
        float o = (float)Q[idx] + acco[vt][i] / lsum[i];
        Q[idx] = (__bf16)o;
      }
  }
}

// ---------------- PMA q = pma_S @ wq + bq (fp32, shared by all items) ----------------
__global__ __launch_bounds__(256) void pma_q_kernel(
    const float* __restrict__ S, const float* __restrict__ wq,
    const float* __restrict__ bq, float* __restrict__ qout)
{
  __shared__ float sS[256];
  int t = threadIdx.x;
  sS[t] = S[t];
  __syncthreads();
  float acc = bq[t];
  for (int k = 0; k < 256; ++k) acc += sS[k] * wq[k * 256 + t];
  qout[t] = acc;
}

// ---------------- PMA decode attention, one block per item ----------------
__global__ __launch_bounds__(256) void pma_attn_kernel(
    const float* __restrict__ qpma, const __bf16* __restrict__ Kb,
    const __bf16* __restrict__ Vb, __bf16* __restrict__ Opma)
{
  __shared__ float sq[256];
  __shared__ float sP[1024];   // [2 heads][512 keys]
  __shared__ float red[256];
  __shared__ float sl[2];
  const int item = blockIdx.x;
  const int t = threadIdx.x;
  sq[t] = qpma[t];
  __syncthreads();

#pragma unroll
  for (int rep = 0; rep < 4; ++rep) {
    int task = rep * 256 + t;
    int h = task >> 9, key = task & 511;
    const __bf16* kr = Kb + ((size_t)item * 512 + key) * 256 + h * 128;
    float s = 0.f;
#pragma unroll
    for (int d8 = 0; d8 < 128; d8 += 8) {
      bf16x8 kv = *(const bf16x8*)(kr + d8);
#pragma unroll
      for (int j = 0; j < 8; ++j) s += sq[h * 128 + d8 + j] * (float)kv[j];
    }
    sP[task] = exp2f(s * LOG2E_O16);
  }
  __syncthreads();
  {
    int h = t >> 7, kb = t & 127;
    float p = 0.f;
#pragma unroll
    for (int j = 0; j < 4; ++j) p += sP[h * 512 + kb + j * 128];
    red[t] = p;
  }
  __syncthreads();
  if (t < 2) {
    float s = 0.f;
    for (int i = 0; i < 128; ++i) s += red[t * 128 + i];
    sl[t] = 1.f / s;
  }
  __syncthreads();
  {
    int h = t >> 7;
    float acc = 0.f;
    for (int key = 0; key < 512; ++key)
      acc += sP[h * 512 + key] * (float)Vb[((size_t)item * 512 + key) * 256 + t];
    Opma[item * 256 + t] = (__bf16)(sq[t] + acc * sl[h]);
  }
}

// ---------------- launch ----------------
extern "C" void kernel_launch(void* const* d_in, const int* in_sizes, int n_in,
                              void* d_out, int out_size, void* d_ws, size_t ws_size,
                              hipStream_t stream)
{
  // inputs: 0 rep_R, 1 GA, 2..9 sab0(wq,bq,wk,bk,wv,bv,wo,bo), 10..17 sab1,
  //         18 pma_S, 19..26 pma(wq,bq,wk,bk,wv,bv,wo,bo), 27..32 mlp(w1,b1,w2,b2,w3,b3)
  const size_t XSZ = (size_t)64 * 512 * 256;   // 8388608 elems
  if (ws_size < 4 * XSZ * sizeof(__bf16) + (1 << 20)) return;  // defensive

  const float* rep = (const float*)d_in[0];
  const float* GA  = (const float*)d_in[1];

  __bf16* X    = (__bf16*)d_ws;
  __bf16* Qb   = X  + XSZ;
  __bf16* Kb   = Qb + XSZ;
  __bf16* Vb   = Kb + XSZ;
  float*  qpma = (float*)(Vb + XSZ);
  __bf16* Opma = (__bf16*)(qpma + 256);
  __bf16* O2   = Opma + 64 * 256;
  __bf16* H1   = O2 + 64 * 256;
  __bf16* H2   = H1 + 64 * 512;

  scale_kernel<<<8192, 256, 0, stream>>>(rep, GA, X);

  for (int sab = 0; sab < 2; ++sab) {
    const float* wq = (const float*)d_in[2 + sab * 8 + 0];
    const float* bq = (const float*)d_in[2 + sab * 8 + 1];
    const float* wk = (const float*)d_in[2 + sab * 8 + 2];
    const float* bk = (const float*)d_in[2 + sab * 8 + 3];
    const float* wvp= (const float*)d_in[2 + sab * 8 + 4];
    const float* bvp= (const float*)d_in[2 + sab * 8 + 5];
    const float* wo = (const float*)d_in[2 + sab * 8 + 6];
    const float* bo = (const float*)d_in[2 + sab * 8 + 7];
    gemm_kernel<0, false><<<dim3(512, 4), 256, 0, stream>>>(X, wq, bq, nullptr, Qb, 32768, 256, 256);
    gemm_kernel<0, false><<<dim3(512, 4), 256, 0, stream>>>(X, wk, bk, nullptr, Kb, 32768, 256, 256);
    gemm_kernel<0, false><<<dim3(512, 4), 256, 0, stream>>>(X, wvp, bvp, nullptr, Vb, 32768, 256, 256);
    attn_sab_kernel<<<dim3(4, 64), 512, 0, stream>>>(Qb, Kb, Vb);
    gemm_kernel<2, false><<<dim3(512, 4), 256, 0, stream>>>(Qb, wo, bo, Qb, X, 32768, 256, 256);
  }

  pma_q_kernel<<<1, 256, 0, stream>>>((const float*)d_in[18], (const float*)d_in[19],
                                      (const float*)d_in[20], qpma);
  gemm_kernel<0, false><<<dim3(512, 4), 256, 0, stream>>>(X, (const float*)d_in[21],
      (const float*)d_in[22], nullptr, Kb, 32768, 256, 256);
  gemm_kernel<0, false><<<dim3(512, 4), 256, 0, stream>>>(X, (const float*)d_in[23],
      (const float*)d_in[24], nullptr, Vb, 32768, 256, 256);
  pma_attn_kernel<<<64, 256, 0, stream>>>(qpma, Kb, Vb, Opma);
  gemm_kernel<2, false><<<dim3(1, 4), 256, 0, stream>>>(Opma, (const float*)d_in[25],
      (const float*)d_in[26], Opma, O2, 64, 256, 256);
  gemm_kernel<1, false><<<dim3(1, 8), 256, 0, stream>>>(O2, (const float*)d_in[27],
      (const float*)d_in[28], nullptr, H1, 64, 512, 256);
  gemm_kernel<1, false><<<dim3(1, 8), 256, 0, stream>>>(H1, (const float*)d_in[29],
      (const float*)d_in[30], nullptr, H2, 64, 512, 512);
  gemm_kernel<0, true><<<dim3(1, 4), 256, 0, stream>>>(H2, (const float*)d_in[31],
      (const float*)d_in[32], nullptr, (float*)d_out, 64, 256, 512);
}

// Round 2
// 279.162 us; speedup vs baseline: 1.1790x; 1.1790x over previous
//
#include <hip/hip_runtime.h>
#include <hip/hip_bf16.h>

typedef __attribute__((ext_vector_type(4))) float  f32x4;
typedef __attribute__((ext_vector_type(8))) __bf16 bf16x8;
typedef __attribute__((ext_vector_type(4))) __bf16 bf16x4;

#define LOG2E_O16 0.09016844005556021f  // log2(e)/16  (scale = 1/sqrt(256))

__device__ __forceinline__ void gload_lds16(const void* g, void* l) {
  __builtin_amdgcn_global_load_lds(
      (const __attribute__((address_space(1))) void*)g,
      (__attribute__((address_space(3))) void*)l, 16, 0, 0);
}

// ---------------- X = GA[g,n] * rep_R, fp32 -> bf16 ----------------
__global__ __launch_bounds__(256) void scale_kernel(
    const float* __restrict__ rep, const float* __restrict__ GA, __bf16* __restrict__ X)
{
  size_t i = (size_t)blockIdx.x * 256 + threadIdx.x;
  size_t e = i * 4;
  f32x4 r = *(const f32x4*)(rep + e);
  int dn = (int)(e >> 8);
  int n  = dn & 511;
  int g  = (dn >> 9) & 15;
  float ga = GA[g * 512 + n];
  bf16x4 o;
  o[0] = (__bf16)(r[0] * ga); o[1] = (__bf16)(r[1] * ga);
  o[2] = (__bf16)(r[2] * ga); o[3] = (__bf16)(r[3] * ga);
  *(bf16x4*)(X + e) = o;
}

// ---------------- weight convert: ten 256x256 fp32 w[K][N] -> bf16 wT[N][K] ----------------
struct WPtrs { const float* w[10]; };
__global__ __launch_bounds__(256) void wconv_kernel(WPtrs ws, __bf16* __restrict__ out)
{
  __shared__ float t[64][65];
  const float* w = ws.w[blockIdx.y];
  __bf16* o = out + (size_t)blockIdx.y * 65536;
  const int tr = (blockIdx.x & 3) * 64, tc = (blockIdx.x >> 2) * 64;
  const int r4 = threadIdx.x >> 6, c = threadIdx.x & 63;
#pragma unroll
  for (int p = 0; p < 16; ++p) {
    int row = p * 4 + r4;
    t[row][c] = w[(size_t)(tr + row) * 256 + tc + c];
  }
  __syncthreads();
#pragma unroll
  for (int p = 0; p < 16; ++p) {
    int row = p * 4 + r4;
    o[(size_t)(tc + row) * 256 + tr + c] = (__bf16)t[c][row];
  }
}

// ---------------- m97-style GEMM: C = epi(A(bf16 [M][K]) @ Bt(bf16 [N][K])^T + bias) ----------------
// 128x128 tile, BK=32, 4 waves, global_load_lds + XOR swizzle. M%128==0, N%128==0, K%32==0.
template<int EPI>   // 0 none, 2 R + relu(acc)
__global__ __launch_bounds__(256) void gemm128_kernel(
    const __bf16* __restrict__ A, const __bf16* __restrict__ Bt,
    const float* __restrict__ bias, const __bf16* __restrict__ R,
    __bf16* __restrict__ C, int M, int N, int K)
{
  __shared__ __align__(16) __bf16 sA[128 * 32];
  __shared__ __align__(16) __bf16 sB[128 * 32];
  const int tid = threadIdx.x, lane = tid & 63, wv = tid >> 6;
  const int l16 = lane & 15, lg = lane >> 4;
  const int wr = (wv >> 1) * 64, wc = (wv & 1) * 64;
  const int bm = blockIdx.x * 128, bn = blockIdx.y * 128;

  const int row_s = tid >> 2;            // staging row per thread (per 4KB round: 64 rows)
  const int kb_s  = (tid & 3) * 16;      // byte within 64B row

  f32x4 acc[4][4] = {};

  for (int k0 = 0; k0 < K; k0 += 32) {
#pragma unroll
    for (int r = 0; r < 2; ++r) {
      int row = r * 64 + row_s;
      int kb  = kb_s ^ (((row >> 1) & 3) << 4);      // pre-swizzled global source
      const char* gA = (const char*)(A  + (size_t)(bm + row) * K + k0) + kb;
      const char* gB = (const char*)(Bt + (size_t)(bn + row) * K + k0) + kb;
      char* dA = (char*)sA + r * 4096 + wv * 1024;   // wave-uniform base, HW adds lane*16
      char* dB = (char*)sB + r * 4096 + wv * 1024;
      gload_lds16(gA, dA);
      gload_lds16(gB, dB);
    }
    __syncthreads();
    bf16x8 af[4], bfr[4];
#pragma unroll
    for (int mi = 0; mi < 4; ++mi) {
      int row = wr + mi * 16 + l16;
      int kb = (lg << 4) ^ (((row >> 1) & 3) << 4);
      af[mi] = *(const bf16x8*)((const char*)sA + row * 64 + kb);
    }
#pragma unroll
    for (int ni = 0; ni < 4; ++ni) {
      int row = wc + ni * 16 + l16;
      int kb = (lg << 4) ^ (((row >> 1) & 3) << 4);
      bfr[ni] = *(const bf16x8*)((const char*)sB + row * 64 + kb);
    }
#pragma unroll
    for (int mi = 0; mi < 4; ++mi)
#pragma unroll
      for (int ni = 0; ni < 4; ++ni)
        acc[mi][ni] = __builtin_amdgcn_mfma_f32_16x16x32_bf16(af[mi], bfr[ni], acc[mi][ni], 0, 0, 0);
    __syncthreads();
  }

#pragma unroll
  for (int mi = 0; mi < 4; ++mi)
#pragma unroll
    for (int ni = 0; ni < 4; ++ni) {
      int col = bn + wc + ni * 16 + l16;
      float bval = bias[col];
      int row0 = bm + wr + mi * 16 + lg * 4;
#pragma unroll
      for (int i = 0; i < 4; ++i) {
        int row = row0 + i;
        float v = acc[mi][ni][i] + bval;
        if (EPI == 2) v = (float)R[(size_t)row * N + col] + fmaxf(v, 0.f);
        C[(size_t)row * N + col] = (__bf16)v;
      }
    }
}

// ---------------- small-M GEMM (M%64==0): fp32 B inline-converted ----------------
template<int EPI, bool OUTF32>
__global__ __launch_bounds__(256) void gemm_kernel(
    const __bf16* __restrict__ A, const float* __restrict__ B,
    const float* __restrict__ bias, const __bf16* __restrict__ R,
    void* __restrict__ Cv, int M, int N, int K)
{
  __shared__ __bf16 sA[64][40];
  __shared__ __bf16 sB[64][40];
  const int tid  = threadIdx.x;
  const int lane = tid & 63;
  const int wv   = tid >> 6;
  const int wr   = (wv >> 1) * 32;
  const int wc   = (wv & 1) * 32;
  const int bm   = blockIdx.x * 64;
  const int bn   = blockIdx.y * 64;
  const int l16  = lane & 15;
  const int lk8  = (lane >> 4) * 8;

  const int a_r = tid >> 2, a_c = (tid & 3) * 8;
  const int b_c = tid & 63, b_k = (tid >> 6) * 8;

  f32x4 acc[2][2] = {};

  for (int k0 = 0; k0 < K; k0 += 32) {
    bf16x8 av = *(const bf16x8*)(A + (size_t)(bm + a_r) * K + k0 + a_c);
    float bvf[8];
#pragma unroll
    for (int j = 0; j < 8; ++j)
      bvf[j] = B[(size_t)(k0 + b_k + j) * N + bn + b_c];
    *(bf16x8*)&sA[a_r][a_c] = av;
    bf16x8 bb;
#pragma unroll
    for (int j = 0; j < 8; ++j) bb[j] = (__bf16)bvf[j];
    *(bf16x8*)&sB[b_c][b_k] = bb;
    __syncthreads();
    bf16x8 af0 = *(const bf16x8*)&sA[wr + l16][lk8];
    bf16x8 af1 = *(const bf16x8*)&sA[wr + 16 + l16][lk8];
    bf16x8 bf0 = *(const bf16x8*)&sB[wc + l16][lk8];
    bf16x8 bf1 = *(const bf16x8*)&sB[wc + 16 + l16][lk8];
    acc[0][0] = __builtin_amdgcn_mfma_f32_16x16x32_bf16(af0, bf0, acc[0][0], 0, 0, 0);
    acc[0][1] = __builtin_amdgcn_mfma_f32_16x16x32_bf16(af0, bf1, acc[0][1], 0, 0, 0);
    acc[1][0] = __builtin_amdgcn_mfma_f32_16x16x32_bf16(af1, bf0, acc[1][0], 0, 0, 0);
    acc[1][1] = __builtin_amdgcn_mfma_f32_16x16x32_bf16(af1, bf1, acc[1][1], 0, 0, 0);
    __syncthreads();
  }

#pragma unroll
  for (int mi = 0; mi < 2; ++mi)
#pragma unroll
    for (int ni = 0; ni < 2; ++ni) {
      int col = bn + wc + ni * 16 + l16;
      float bval = bias[col];
      int row0 = bm + wr + mi * 16 + (lane >> 4) * 4;
#pragma unroll
      for (int i = 0; i < 4; ++i) {
        int row = row0 + i;
        float v = acc[mi][ni][i] + bval;
        if (EPI == 1) v = fmaxf(v, 0.f);
        if (EPI == 2) v = (float)R[(size_t)row * N + col] + fmaxf(v, 0.f);
        if (OUTF32) ((float*)Cv)[(size_t)row * N + col] = v;
        else        ((__bf16*)Cv)[(size_t)row * N + col] = (__bf16)v;
      }
    }
}

// ---------------- fused SAB attention ----------------
// grid (8, 64): blockIdx.x = head(0..3) | qhalf<<2 ; blockIdx.y = item.
// 8 waves x 32 q-rows. K/V chunked 128 keys, swapped QK^T (P lane-local per q-col).
__global__ __launch_bounds__(512, 4) void attn_sab_kernel(
    __bf16* __restrict__ Q, const __bf16* __restrict__ Kb, const __bf16* __restrict__ Vb)
{
  __shared__ __align__(16) __bf16 sK[128][72];    // [key][d] chunk
  __shared__ __align__(16) __bf16 sV[64][136];    // [d][key] chunk, transposed
  __shared__ __align__(16) __bf16 sP[8][16][72];  // per-wave [q16][k64]

  const int head = blockIdx.x & 3;
  const int qh   = blockIdx.x >> 2;
  const int item = blockIdx.y;
  const int tid  = threadIdx.x;
  const int lane = tid & 63;
  const int wv   = tid >> 6;
  const int l16  = lane & 15;
  const int lg   = lane >> 4;
  const size_t base = (size_t)item * (512 * 256) + (size_t)head * 64;
  const int qbase_row = qh * 256 + wv * 32;

  f32x4 acco[2][4] = {};
  float lsum[2] = {0.f, 0.f};

  const int kr  = tid >> 3, kc8 = (tid & 7) * 8;
  const int vch = tid & 63, vk8 = (tid >> 6) * 8;

  for (int c = 0; c < 4; ++c) {
    const int kc0 = c * 128;
    if (c) __syncthreads();
#pragma unroll
    for (int pass = 0; pass < 2; ++pass) {
      int rowl = pass * 64 + kr;
      *(bf16x8*)&sK[rowl][kc8] = *(const bf16x8*)(Kb + base + (size_t)(kc0 + rowl) * 256 + kc8);
      int key0 = pass * 64 + vk8;
      bf16x8 vv;
#pragma unroll
      for (int j = 0; j < 8; ++j)
        vv[j] = Vb[base + (size_t)(kc0 + key0 + j) * 256 + vch];
      *(bf16x8*)&sV[vch][key0] = vv;
    }
    __syncthreads();

#pragma unroll
    for (int qb = 0; qb < 2; ++qb) {
      const size_t qrow = base + (size_t)(qbase_row + qb * 16 + l16) * 256;
      bf16x8 aq0 = *(const bf16x8*)(Q + qrow + lg * 8);
      bf16x8 aq1 = *(const bf16x8*)(Q + qrow + 32 + lg * 8);
#pragma unroll
      for (int half = 0; half < 2; ++half) {
#pragma unroll
        for (int st = 0; st < 4; ++st) {
          int krl = half * 64 + st * 16 + l16;
          f32x4 s = {};
          s = __builtin_amdgcn_mfma_f32_16x16x32_bf16(*(const bf16x8*)&sK[krl][lg * 8], aq0, s, 0, 0, 0);
          s = __builtin_amdgcn_mfma_f32_16x16x32_bf16(*(const bf16x8*)&sK[krl][32 + lg * 8], aq1, s, 0, 0, 0);
          bf16x4 pv4;
          float ls = 0.f;
#pragma unroll
          for (int i = 0; i < 4; ++i) {
            float p = exp2f(s[i] * LOG2E_O16);
            ls += p;
            pv4[i] = (__bf16)p;
          }
          lsum[qb] += ls;
          *(bf16x4*)&sP[wv][l16][st * 16 + lg * 4] = pv4;   // 4 consecutive k: one b64
        }
#pragma unroll
        for (int kk = 0; kk < 2; ++kk) {
          bf16x8 ap = *(const bf16x8*)&sP[wv][l16][kk * 32 + lg * 8];
#pragma unroll
          for (int vt = 0; vt < 4; ++vt) {
            bf16x8 bvv = *(const bf16x8*)&sV[vt * 16 + l16][half * 64 + kk * 32 + lg * 8];
            acco[qb][vt] = __builtin_amdgcn_mfma_f32_16x16x32_bf16(ap, bvv, acco[qb][vt], 0, 0, 0);
          }
        }
      }
    }
  }

#pragma unroll
  for (int qb = 0; qb < 2; ++qb) {
    float t = lsum[qb];
    t += __shfl_xor(t, 16, 64);
    t += __shfl_xor(t, 32, 64);          // total for q = l16
#pragma unroll
    for (int i = 0; i < 4; ++i) {
      float tot = __shfl(t, lg * 4 + i, 64);   // sum for q_local = lg*4+i
      float inv = 1.0f / tot;
      int row = qbase_row + qb * 16 + lg * 4 + i;
#pragma unroll
      for (int vt = 0; vt < 4; ++vt) {
        size_t idx = base + (size_t)row * 256 + vt * 16 + l16;
        Q[idx] = (__bf16)((float)Q[idx] + acco[qb][vt][i] * inv);
      }
    }
  }
}

// ---------------- PMA q = pma_S @ wq + bq ----------------
__global__ __launch_bounds__(256) void pma_q_kernel(
    const float* __restrict__ S, const float* __restrict__ wq,
    const float* __restrict__ bq, float* __restrict__ qout)
{
  __shared__ float sS[256];
  int t = threadIdx.x;
  sS[t] = S[t];
  __syncthreads();
  float acc = bq[t];
  for (int k = 0; k < 256; ++k) acc += sS[k] * wq[k * 256 + t];
  qout[t] = acc;
}

// ---------------- PMA decode attention ----------------
__global__ __launch_bounds__(256) void pma_attn_kernel(
    const float* __restrict__ qpma, const __bf16* __restrict__ Kb,
    const __bf16* __restrict__ Vb, __bf16* __restrict__ Opma)
{
  __shared__ float sq[256];
  __shared__ float sP[1024];
  __shared__ float red[256];
  __shared__ float sl[2];
  const int item = blockIdx.x;
  const int t = threadIdx.x;
  sq[t] = qpma[t];
  __syncthreads();

#pragma unroll
  for (int rep = 0; rep < 4; ++rep) {
    int task = rep * 256 + t;
    int h = task >> 9, key = task & 511;
    const __bf16* kr = Kb + ((size_t)item * 512 + key) * 256 + h * 128;
    float s = 0.f;
#pragma unroll
    for (int d8 = 0; d8 < 128; d8 += 8) {
      bf16x8 kv = *(const bf16x8*)(kr + d8);
#pragma unroll
      for (int j = 0; j < 8; ++j) s += sq[h * 128 + d8 + j] * (float)kv[j];
    }
    sP[task] = exp2f(s * LOG2E_O16);
  }
  __syncthreads();
  {
    int h = t >> 7, kb = t & 127;
    float p = 0.f;
#pragma unroll
    for (int j = 0; j < 4; ++j) p += sP[h * 512 + kb + j * 128];
    red[t] = p;
  }
  __syncthreads();
  if (t < 2) {
    float s = 0.f;
    for (int i = 0; i < 128; ++i) s += red[t * 128 + i];
    sl[t] = 1.f / s;
  }
  __syncthreads();
  {
    int h = t >> 7;
    float acc = 0.f;
    for (int key = 0; key < 512; ++key)
      acc += sP[h * 512 + key] * (float)Vb[((size_t)item * 512 + key) * 256 + t];
    Opma[item * 256 + t] = (__bf16)(sq[t] + acc * sl[h]);
  }
}

// ---------------- launch ----------------
extern "C" void kernel_launch(void* const* d_in, const int* in_sizes, int n_in,
                              void* d_out, int out_size, void* d_ws, size_t ws_size,
                              hipStream_t stream)
{
  const size_t XSZ = (size_t)64 * 512 * 256;
  if (ws_size < 4 * XSZ * sizeof(__bf16) + (2u << 20)) return;

  const float* rep = (const float*)d_in[0];
  const float* GA  = (const float*)d_in[1];

  __bf16* X    = (__bf16*)d_ws;
  __bf16* Qb   = X  + XSZ;
  __bf16* Kb   = Qb + XSZ;
  __bf16* Vb   = Kb + XSZ;
  __bf16* wT   = Vb + XSZ;                 // 10 x 256x256 bf16 (row = out ch, col = k)
  float*  qpma = (float*)(wT + 10 * 65536);
  __bf16* Opma = (__bf16*)(qpma + 256);
  __bf16* O2   = Opma + 64 * 256;
  __bf16* H1   = O2 + 64 * 256;
  __bf16* H2   = H1 + 64 * 512;

  // weight conversion: sab0 q,k,v,o ; sab1 q,k,v,o ; pma k ; pma v
  WPtrs wp;
  for (int s = 0; s < 2; ++s)
    for (int j = 0; j < 4; ++j)
      wp.w[s * 4 + j] = (const float*)d_in[2 + s * 8 + j * 2];
  wp.w[8] = (const float*)d_in[21];
  wp.w[9] = (const float*)d_in[23];
  wconv_kernel<<<dim3(16, 10), 256, 0, stream>>>(wp, wT);

  scale_kernel<<<8192, 256, 0, stream>>>(rep, GA, X);

  for (int sab = 0; sab < 2; ++sab) {
    const __bf16* wq = wT + (size_t)(sab * 4 + 0) * 65536;
    const __bf16* wk = wT + (size_t)(sab * 4 + 1) * 65536;
    const __bf16* wvp= wT + (size_t)(sab * 4 + 2) * 65536;
    const __bf16* wo = wT + (size_t)(sab * 4 + 3) * 65536;
    const float* bq = (const float*)d_in[2 + sab * 8 + 1];
    const float* bk = (const float*)d_in[2 + sab * 8 + 3];
    const float* bv = (const float*)d_in[2 + sab * 8 + 5];
    const float* bo = (const float*)d_in[2 + sab * 8 + 7];
    gemm128_kernel<0><<<dim3(256, 2), 256, 0, stream>>>(X, wq, bq, nullptr, Qb, 32768, 256, 256);
    gemm128_kernel<0><<<dim3(256, 2), 256, 0, stream>>>(X, wk, bk, nullptr, Kb, 32768, 256, 256);
    gemm128_kernel<0><<<dim3(256, 2), 256, 0, stream>>>(X, wvp, bv, nullptr, Vb, 32768, 256, 256);
    attn_sab_kernel<<<dim3(8, 64), 512, 0, stream>>>(Qb, Kb, Vb);
    gemm128_kernel<2><<<dim3(256, 2), 256, 0, stream>>>(Qb, wo, bo, Qb, X, 32768, 256, 256);
  }

  pma_q_kernel<<<1, 256, 0, stream>>>((const float*)d_in[18], (const float*)d_in[19],
                                      (const float*)d_in[20], qpma);
  gemm128_kernel<0><<<dim3(256, 2), 256, 0, stream>>>(X, wT + (size_t)8 * 65536,
      (const float*)d_in[22], nullptr, Kb, 32768, 256, 256);
  gemm128_kernel<0><<<dim3(256, 2), 256, 0, stream>>>(X, wT + (size_t)9 * 65536,
      (const float*)d_in[24], nullptr, Vb, 32768, 256, 256);
  pma_attn_kernel<<<64, 256, 0, stream>>>(qpma, Kb, Vb, Opma);
  gemm_kernel<2, false><<<dim3(1, 4), 256, 0, stream>>>(Opma, (const float*)d_in[25],
      (const float*)d_in[26], Opma, O2, 64, 256, 256);
  gemm_kernel<1, false><<<dim3(1, 8), 256, 0, stream>>>(O2, (const float*)d_in[27],
      (const float*)d_in[28], nullptr, H1, 64, 512, 256);
  gemm_kernel<1, false><<<dim3(1, 8), 256, 0, stream>>>(H1, (const float*)d_in[29],
      (const float*)d_in[30], nullptr, H2, 64, 512, 512);
  gemm_kernel<0, true><<<dim3(1, 4), 256, 0, stream>>>(H2, (const float*)d_in[31],
      (const float*)d_in[32], nullptr, (float*)d_out, 64, 256, 512);
}

// Round 3
// 248.129 us; speedup vs baseline: 1.3264x; 1.1251x over previous
//
#include <hip/hip_runtime.h>
#include <hip/hip_bf16.h>

typedef __attribute__((ext_vector_type(4))) float  f32x4;
typedef __attribute__((ext_vector_type(8))) __bf16 bf16x8;
typedef __attribute__((ext_vector_type(4))) __bf16 bf16x4;

#define LOG2E_O16 0.09016844005556021f  // log2(e)/16  (scale = 1/sqrt(256))

__device__ __forceinline__ void gload_lds16(const void* g, void* l) {
  __builtin_amdgcn_global_load_lds(
      (const __attribute__((address_space(1))) void*)g,
      (__attribute__((address_space(3))) void*)l, 16, 0, 0);
}

// ---------------- X = GA[g,n] * rep_R, fp32 -> bf16 ----------------
__global__ __launch_bounds__(256) void scale_kernel(
    const float* __restrict__ rep, const float* __restrict__ GA, __bf16* __restrict__ X)
{
  size_t i = (size_t)blockIdx.x * 256 + threadIdx.x;
  size_t e = i * 4;
  f32x4 r = *(const f32x4*)(rep + e);
  int dn = (int)(e >> 8);
  int n  = dn & 511;
  int g  = (dn >> 9) & 15;
  float ga = GA[g * 512 + n];
  bf16x4 o;
  o[0] = (__bf16)(r[0] * ga); o[1] = (__bf16)(r[1] * ga);
  o[2] = (__bf16)(r[2] * ga); o[3] = (__bf16)(r[3] * ga);
  *(bf16x4*)(X + e) = o;
}

// ---------------- weight convert: ten 256x256 fp32 w[K][N] -> bf16 wT[N][K] ----------------
struct WPtrs { const float* w[10]; };
__global__ __launch_bounds__(256) void wconv_kernel(WPtrs ws, __bf16* __restrict__ out)
{
  __shared__ float t[64][65];
  const float* w = ws.w[blockIdx.y];
  __bf16* o = out + (size_t)blockIdx.y * 65536;
  const int tr = (blockIdx.x & 3) * 64, tc = (blockIdx.x >> 2) * 64;
  const int r4 = threadIdx.x >> 6, c = threadIdx.x & 63;
#pragma unroll
  for (int p = 0; p < 16; ++p) {
    int row = p * 4 + r4;
    t[row][c] = w[(size_t)(tr + row) * 256 + tc + c];
  }
  __syncthreads();
#pragma unroll
  for (int p = 0; p < 16; ++p) {
    int row = p * 4 + r4;
    o[(size_t)(tc + row) * 256 + tr + c] = (__bf16)t[c][row];
  }
}

// ---------------- fused multi-output GEMM: out[j] = A @ Bt[j]^T + bias[j] ----------------
// A bf16 [M][K], Bt bf16 [256][K], out bf16 [M][256]. 128x128 tile, BK=32, XCD swizzle.
struct QKV3 {
  const __bf16* Bt[3];
  const float* bias[3];
  __bf16* out[3];
};

template<int NW>
__global__ __launch_bounds__(256) void gemmqkv_kernel(
    const __bf16* __restrict__ A, QKV3 args, int K)
{
  __shared__ __align__(16) __bf16 sA[128 * 32];
  __shared__ __align__(16) __bf16 sB[128 * 32];
  const int tid = threadIdx.x, lane = tid & 63, wv = tid >> 6;
  const int l16 = lane & 15, lg = lane >> 4;
  const int wr = (wv >> 1) * 64, wc = (wv & 1) * 64;

  const int nblk = gridDim.x, cpx = nblk >> 3, orig = blockIdx.x;
  const int wg  = (orig & 7) * cpx + (orig >> 3);       // bijective XCD swizzle
  const int r   = wg / (2 * NW), rem = wg % (2 * NW);
  const int j   = rem >> 1;
  const int bm  = r * 128, bn = (rem & 1) * 128;
  const __bf16* __restrict__ Bt = args.Bt[j];

  const int row_s = tid >> 2;
  const int kb_s  = (tid & 3) * 16;

  f32x4 acc[4][4] = {};

  for (int k0 = 0; k0 < K; k0 += 32) {
#pragma unroll
    for (int rr = 0; rr < 2; ++rr) {
      int row = rr * 64 + row_s;
      int kb  = kb_s ^ (((row >> 1) & 3) << 4);
      const char* gA = (const char*)(A  + (size_t)(bm + row) * K + k0) + kb;
      const char* gB = (const char*)(Bt + (size_t)(bn + row) * K + k0) + kb;
      char* dA = (char*)sA + rr * 4096 + wv * 1024;
      char* dB = (char*)sB + rr * 4096 + wv * 1024;
      gload_lds16(gA, dA);
      gload_lds16(gB, dB);
    }
    __syncthreads();
    bf16x8 af[4], bfr[4];
#pragma unroll
    for (int mi = 0; mi < 4; ++mi) {
      int row = wr + mi * 16 + l16;
      int kb = (lg << 4) ^ (((row >> 1) & 3) << 4);
      af[mi] = *(const bf16x8*)((const char*)sA + row * 64 + kb);
    }
#pragma unroll
    for (int ni = 0; ni < 4; ++ni) {
      int row = wc + ni * 16 + l16;
      int kb = (lg << 4) ^ (((row >> 1) & 3) << 4);
      bfr[ni] = *(const bf16x8*)((const char*)sB + row * 64 + kb);
    }
#pragma unroll
    for (int mi = 0; mi < 4; ++mi)
#pragma unroll
      for (int ni = 0; ni < 4; ++ni)
        acc[mi][ni] = __builtin_amdgcn_mfma_f32_16x16x32_bf16(af[mi], bfr[ni], acc[mi][ni], 0, 0, 0);
    __syncthreads();
  }

  const float* bias = args.bias[j];
  __bf16* C = args.out[j];
#pragma unroll
  for (int mi = 0; mi < 4; ++mi)
#pragma unroll
    for (int ni = 0; ni < 4; ++ni) {
      int col = bn + wc + ni * 16 + l16;
      float bval = bias[col];
      int row0 = bm + wr + mi * 16 + lg * 4;
#pragma unroll
      for (int i = 0; i < 4; ++i) {
        int row = row0 + i;
        C[(size_t)row * 256 + col] = (__bf16)(acc[mi][ni][i] + bval);
      }
    }
}

// ---------------- m97-style GEMM (O-proj): C = R + relu(A @ Bt^T + bias) ----------------
// 1-D grid = (M/128)*2 blocks, N=256, XCD swizzle.
__global__ __launch_bounds__(256) void gemm128_kernel(
    const __bf16* __restrict__ A, const __bf16* __restrict__ Bt,
    const float* __restrict__ bias, const __bf16* __restrict__ R,
    __bf16* __restrict__ C, int K)
{
  __shared__ __align__(16) __bf16 sA[128 * 32];
  __shared__ __align__(16) __bf16 sB[128 * 32];
  const int tid = threadIdx.x, lane = tid & 63, wv = tid >> 6;
  const int l16 = lane & 15, lg = lane >> 4;
  const int wr = (wv >> 1) * 64, wc = (wv & 1) * 64;

  const int nblk = gridDim.x, cpx = nblk >> 3, orig = blockIdx.x;
  const int wg  = (orig & 7) * cpx + (orig >> 3);
  const int bm  = (wg >> 1) * 128, bn = (wg & 1) * 128;

  const int row_s = tid >> 2;
  const int kb_s  = (tid & 3) * 16;

  f32x4 acc[4][4] = {};

  for (int k0 = 0; k0 < K; k0 += 32) {
#pragma unroll
    for (int rr = 0; rr < 2; ++rr) {
      int row = rr * 64 + row_s;
      int kb  = kb_s ^ (((row >> 1) & 3) << 4);
      const char* gA = (const char*)(A  + (size_t)(bm + row) * K + k0) + kb;
      const char* gB = (const char*)(Bt + (size_t)(bn + row) * K + k0) + kb;
      char* dA = (char*)sA + rr * 4096 + wv * 1024;
      char* dB = (char*)sB + rr * 4096 + wv * 1024;
      gload_lds16(gA, dA);
      gload_lds16(gB, dB);
    }
    __syncthreads();
    bf16x8 af[4], bfr[4];
#pragma unroll
    for (int mi = 0; mi < 4; ++mi) {
      int row = wr + mi * 16 + l16;
      int kb = (lg << 4) ^ (((row >> 1) & 3) << 4);
      af[mi] = *(const bf16x8*)((const char*)sA + row * 64 + kb);
    }
#pragma unroll
    for (int ni = 0; ni < 4; ++ni) {
      int row = wc + ni * 16 + l16;
      int kb = (lg << 4) ^ (((row >> 1) & 3) << 4);
      bfr[ni] = *(const bf16x8*)((const char*)sB + row * 64 + kb);
    }
#pragma unroll
    for (int mi = 0; mi < 4; ++mi)
#pragma unroll
      for (int ni = 0; ni < 4; ++ni)
        acc[mi][ni] = __builtin_amdgcn_mfma_f32_16x16x32_bf16(af[mi], bfr[ni], acc[mi][ni], 0, 0, 0);
    __syncthreads();
  }

#pragma unroll
  for (int mi = 0; mi < 4; ++mi)
#pragma unroll
    for (int ni = 0; ni < 4; ++ni) {
      int col = bn + wc + ni * 16 + l16;
      float bval = bias[col];
      int row0 = bm + wr + mi * 16 + lg * 4;
#pragma unroll
      for (int i = 0; i < 4; ++i) {
        int row = row0 + i;
        float v = fmaxf(acc[mi][ni][i] + bval, 0.f);
        C[(size_t)row * 256 + col] = (__bf16)((float)R[(size_t)row * 256 + col] + v);
      }
    }
}

// ---------------- small-M GEMM (MLP): fp32 B inline-converted ----------------
template<int EPI, bool OUTF32>
__global__ __launch_bounds__(256) void gemm_kernel(
    const __bf16* __restrict__ A, const float* __restrict__ B,
    const float* __restrict__ bias, const __bf16* __restrict__ R,
    void* __restrict__ Cv, int M, int N, int K)
{
  __shared__ __bf16 sA[64][40];
  __shared__ __bf16 sB[64][40];
  const int tid  = threadIdx.x;
  const int lane = tid & 63;
  const int wv   = tid >> 6;
  const int wr   = (wv >> 1) * 32;
  const int wc   = (wv & 1) * 32;
  const int bm   = blockIdx.x * 64;
  const int bn   = blockIdx.y * 64;
  const int l16  = lane & 15;
  const int lk8  = (lane >> 4) * 8;

  const int a_r = tid >> 2, a_c = (tid & 3) * 8;
  const int b_c = tid & 63, b_k = (tid >> 6) * 8;

  f32x4 acc[2][2] = {};

  for (int k0 = 0; k0 < K; k0 += 32) {
    bf16x8 av = *(const bf16x8*)(A + (size_t)(bm + a_r) * K + k0 + a_c);
    float bvf[8];
#pragma unroll
    for (int j = 0; j < 8; ++j)
      bvf[j] = B[(size_t)(k0 + b_k + j) * N + bn + b_c];
    *(bf16x8*)&sA[a_r][a_c] = av;
    bf16x8 bb;
#pragma unroll
    for (int j = 0; j < 8; ++j) bb[j] = (__bf16)bvf[j];
    *(bf16x8*)&sB[b_c][b_k] = bb;
    __syncthreads();
    bf16x8 af0 = *(const bf16x8*)&sA[wr + l16][lk8];
    bf16x8 af1 = *(const bf16x8*)&sA[wr + 16 + l16][lk8];
    bf16x8 bf0 = *(const bf16x8*)&sB[wc + l16][lk8];
    bf16x8 bf1 = *(const bf16x8*)&sB[wc + 16 + l16][lk8];
    acc[0][0] = __builtin_amdgcn_mfma_f32_16x16x32_bf16(af0, bf0, acc[0][0], 0, 0, 0);
    acc[0][1] = __builtin_amdgcn_mfma_f32_16x16x32_bf16(af0, bf1, acc[0][1], 0, 0, 0);
    acc[1][0] = __builtin_amdgcn_mfma_f32_16x16x32_bf16(af1, bf0, acc[1][0], 0, 0, 0);
    acc[1][1] = __builtin_amdgcn_mfma_f32_16x16x32_bf16(af1, bf1, acc[1][1], 0, 0, 0);
    __syncthreads();
  }

#pragma unroll
  for (int mi = 0; mi < 2; ++mi)
#pragma unroll
    for (int ni = 0; ni < 2; ++ni) {
      int col = bn + wc + ni * 16 + l16;
      float bval = bias[col];
      int row0 = bm + wr + mi * 16 + (lane >> 4) * 4;
#pragma unroll
      for (int i = 0; i < 4; ++i) {
        int row = row0 + i;
        float v = acc[mi][ni][i] + bval;
        if (EPI == 1) v = fmaxf(v, 0.f);
        if (EPI == 2) v = (float)R[(size_t)row * N + col] + fmaxf(v, 0.f);
        if (OUTF32) ((float*)Cv)[(size_t)row * N + col] = v;
        else        ((__bf16*)Cv)[(size_t)row * N + col] = (__bf16)v;
      }
    }
}

// ---------------- fused SAB attention ----------------
// 1-D grid of 512 blocks; XCD swizzle puts both q-halves of one (head,item)
// consecutively on the same XCD (second K/V read hits L2).
// 8 waves x 32 q-rows; K/V chunked 128 keys, async-staged (T14); swapped QK^T.
__global__ __launch_bounds__(512, 2) void attn_sab_kernel(
    __bf16* __restrict__ Q, const __bf16* __restrict__ Kb, const __bf16* __restrict__ Vb)
{
  __shared__ __align__(16) __bf16 sK[128][72];
  __shared__ __align__(16) __bf16 sV[64][136];
  __shared__ __align__(16) __bf16 sP[8][16][72];

  const int orig = blockIdx.x;                 // 512 blocks
  const int wg   = (orig & 7) * 64 + (orig >> 3);
  const int qh   = wg & 1;
  const int pair = wg >> 1;                    // 0..255
  const int head = pair & 3;
  const int item = pair >> 2;

  const int tid  = threadIdx.x;
  const int lane = tid & 63;
  const int wv   = tid >> 6;
  const int l16  = lane & 15;
  const int lg   = lane >> 4;
  const size_t base = (size_t)item * (512 * 256) + (size_t)head * 64;
  const int qrow0 = qh * 256 + wv * 32;

  // hoisted Q fragments: [qb][d-half]
  bf16x8 aq[2][2];
#pragma unroll
  for (int qb = 0; qb < 2; ++qb) {
    const size_t qrow = base + (size_t)(qrow0 + qb * 16 + l16) * 256;
    aq[qb][0] = *(const bf16x8*)(Q + qrow + lg * 8);
    aq[qb][1] = *(const bf16x8*)(Q + qrow + 32 + lg * 8);
  }

  f32x4 acco[2][4] = {};
  float lsum[2] = {0.f, 0.f};

  const int kr  = tid >> 3, kc8 = (tid & 7) * 8;
  const int vch = tid & 63, vk8 = (tid >> 6) * 8;

  bf16x8 kreg[2], vreg[2];

#define LOADC(cc) do {                                                             \
    _Pragma("unroll")                                                              \
    for (int p = 0; p < 2; ++p) {                                                  \
      kreg[p] = *(const bf16x8*)(Kb + base + (size_t)((cc)*128 + p*64 + kr)*256 + kc8); \
      bf16x8 vv;                                                                   \
      _Pragma("unroll")                                                            \
      for (int jj = 0; jj < 8; ++jj)                                               \
        vv[jj] = Vb[base + (size_t)((cc)*128 + p*64 + vk8 + jj)*256 + vch];        \
      vreg[p] = vv;                                                                \
    } } while (0)

  LOADC(0);

  for (int c = 0; c < 4; ++c) {
    if (c) __syncthreads();                    // all waves done reading prev chunk
#pragma unroll
    for (int p = 0; p < 2; ++p) {
      *(bf16x8*)&sK[p * 64 + kr][kc8] = kreg[p];
      *(bf16x8*)&sV[vch][p * 64 + vk8] = vreg[p];
    }
    __syncthreads();
    if (c < 3) LOADC(c + 1);                   // overlaps with compute below

#pragma unroll
    for (int qb = 0; qb < 2; ++qb) {
#pragma unroll
      for (int half = 0; half < 2; ++half) {
        f32x4 s[4];
#pragma unroll
        for (int st = 0; st < 4; ++st) {
          int krl = half * 64 + st * 16 + l16;
          f32x4 z = {};
          s[st] = __builtin_amdgcn_mfma_f32_16x16x32_bf16(
                      *(const bf16x8*)&sK[krl][lg * 8], aq[qb][0], z, 0, 0, 0);
        }
#pragma unroll
        for (int st = 0; st < 4; ++st) {
          int krl = half * 64 + st * 16 + l16;
          s[st] = __builtin_amdgcn_mfma_f32_16x16x32_bf16(
                      *(const bf16x8*)&sK[krl][32 + lg * 8], aq[qb][1], s[st], 0, 0, 0);
        }
#pragma unroll
        for (int st = 0; st < 4; ++st) {
          bf16x4 pv4;
          float ls = 0.f;
#pragma unroll
          for (int i = 0; i < 4; ++i) {
            float p = __builtin_amdgcn_exp2f(s[st][i] * LOG2E_O16);
            ls += p;
            pv4[i] = (__bf16)p;
          }
          lsum[qb] += ls;
          *(bf16x4*)&sP[wv][l16][st * 16 + lg * 4] = pv4;
        }
#pragma unroll
        for (int kk = 0; kk < 2; ++kk) {
          bf16x8 ap = *(const bf16x8*)&sP[wv][l16][kk * 32 + lg * 8];
#pragma unroll
          for (int vt = 0; vt < 4; ++vt) {
            bf16x8 bvv = *(const bf16x8*)&sV[vt * 16 + l16][half * 64 + kk * 32 + lg * 8];
            acco[qb][vt] = __builtin_amdgcn_mfma_f32_16x16x32_bf16(ap, bvv, acco[qb][vt], 0, 0, 0);
          }
        }
      }
    }
  }
#undef LOADC

#pragma unroll
  for (int qb = 0; qb < 2; ++qb) {
    float t = lsum[qb];
    t += __shfl_xor(t, 16, 64);
    t += __shfl_xor(t, 32, 64);
#pragma unroll
    for (int i = 0; i < 4; ++i) {
      float tot = __shfl(t, lg * 4 + i, 64);
      float inv = 1.0f / tot;
      int row = qrow0 + qb * 16 + lg * 4 + i;
#pragma unroll
      for (int vt = 0; vt < 4; ++vt) {
        size_t idx = base + (size_t)row * 256 + vt * 16 + l16;
        Q[idx] = (__bf16)((float)Q[idx] + acco[qb][vt][i] * inv);
      }
    }
  }
}

// ---------------- PMA q = pma_S @ wq + bq ----------------
__global__ __launch_bounds__(256) void pma_q_kernel(
    const float* __restrict__ S, const float* __restrict__ wq,
    const float* __restrict__ bq, float* __restrict__ qout)
{
  __shared__ float sS[256];
  int t = threadIdx.x;
  sS[t] = S[t];
  __syncthreads();
  float acc = bq[t];
  for (int k = 0; k < 256; ++k) acc += sS[k] * wq[k * 256 + t];
  qout[t] = acc;
}

// ---------------- PMA decode attention ----------------
__global__ __launch_bounds__(256) void pma_attn_kernel(
    const float* __restrict__ qpma, const __bf16* __restrict__ Kb,
    const __bf16* __restrict__ Vb, __bf16* __restrict__ Opma)
{
  __shared__ float sq[256];
  __shared__ float sP[1024];
  __shared__ float red[256];
  __shared__ float sl[2];
  const int item = blockIdx.x;
  const int t = threadIdx.x;
  sq[t] = qpma[t];
  __syncthreads();

#pragma unroll
  for (int rep = 0; rep < 4; ++rep) {
    int task = rep * 256 + t;
    int h = task >> 9, key = task & 511;
    const __bf16* kr = Kb + ((size_t)item * 512 + key) * 256 + h * 128;
    float s = 0.f;
#pragma unroll
    for (int d8 = 0; d8 < 128; d8 += 8) {
      bf16x8 kv = *(const bf16x8*)(kr + d8);
#pragma unroll
      for (int j = 0; j < 8; ++j) s += sq[h * 128 + d8 + j] * (float)kv[j];
    }
    sP[task] = __builtin_amdgcn_exp2f(s * LOG2E_O16);
  }
  __syncthreads();
  {
    int h = t >> 7, kb = t & 127;
    float p = 0.f;
#pragma unroll
    for (int j = 0; j < 4; ++j) p += sP[h * 512 + kb + j * 128];
    red[t] = p;
  }
  __syncthreads();
  if (t < 2) {
    float s = 0.f;
    for (int i = 0; i < 128; ++i) s += red[t * 128 + i];
    sl[t] = 1.f / s;
  }
  __syncthreads();
  {
    int h = t >> 7;
    float acc = 0.f;
    for (int key = 0; key < 512; ++key)
      acc += sP[h * 512 + key] * (float)Vb[((size_t)item * 512 + key) * 256 + t];
    Opma[item * 256 + t] = (__bf16)(sq[t] + acc * sl[h]);
  }
}

// ---------------- launch ----------------
extern "C" void kernel_launch(void* const* d_in, const int* in_sizes, int n_in,
                              void* d_out, int out_size, void* d_ws, size_t ws_size,
                              hipStream_t stream)
{
  const size_t XSZ = (size_t)64 * 512 * 256;
  if (ws_size < 4 * XSZ * sizeof(__bf16) + (4u << 20)) return;

  const float* rep = (const float*)d_in[0];
  const float* GA  = (const float*)d_in[1];

  __bf16* X    = (__bf16*)d_ws;
  __bf16* Qb   = X  + XSZ;
  __bf16* Kb   = Qb + XSZ;
  __bf16* Vb   = Kb + XSZ;
  __bf16* wT   = Vb + XSZ;                 // 10 x 256x256 bf16 (row = out ch, col = k)
  float*  qpma = (float*)(wT + 10 * 65536);
  __bf16* Opma = (__bf16*)(qpma + 256);
  __bf16* O2   = Opma + 64 * 256;
  __bf16* H1   = O2 + 64 * 256;
  __bf16* H2   = H1 + 64 * 512;

  // weight conversion: sab0 q,k,v,o ; sab1 q,k,v,o ; pma k ; pma v
  WPtrs wp;
  for (int s = 0; s < 2; ++s)
    for (int j = 0; j < 4; ++j)
      wp.w[s * 4 + j] = (const float*)d_in[2 + s * 8 + j * 2];
  wp.w[8] = (const float*)d_in[21];
  wp.w[9] = (const float*)d_in[23];
  wconv_kernel<<<dim3(16, 10), 256, 0, stream>>>(wp, wT);

  scale_kernel<<<8192, 256, 0, stream>>>(rep, GA, X);

  for (int sab = 0; sab < 2; ++sab) {
    QKV3 a;
    a.Bt[0] = wT + (size_t)(sab * 4 + 0) * 65536;
    a.Bt[1] = wT + (size_t)(sab * 4 + 1) * 65536;
    a.Bt[2] = wT + (size_t)(sab * 4 + 2) * 65536;
    a.bias[0] = (const float*)d_in[2 + sab * 8 + 1];
    a.bias[1] = (const float*)d_in[2 + sab * 8 + 3];
    a.bias[2] = (const float*)d_in[2 + sab * 8 + 5];
    a.out[0] = Qb; a.out[1] = Kb; a.out[2] = Vb;
    gemmqkv_kernel<3><<<1536, 256, 0, stream>>>(X, a, 256);
    attn_sab_kernel<<<512, 512, 0, stream>>>(Qb, Kb, Vb);
    gemm128_kernel<<<512, 256, 0, stream>>>(Qb, wT + (size_t)(sab * 4 + 3) * 65536,
        (const float*)d_in[2 + sab * 8 + 7], Qb, X, 256);
  }

  pma_q_kernel<<<1, 256, 0, stream>>>((const float*)d_in[18], (const float*)d_in[19],
                                      (const float*)d_in[20], qpma);
  {
    QKV3 a;
    a.Bt[0] = wT + (size_t)8 * 65536;
    a.Bt[1] = wT + (size_t)9 * 65536;
    a.Bt[2] = wT;  // unused
    a.bias[0] = (const float*)d_in[22];
    a.bias[1] = (const float*)d_in[24];
    a.bias[2] = (const float*)d_in[22];  // unused
    a.out[0] = Kb; a.out[1] = Vb; a.out[2] = Kb;  // slot 2 unused
    gemmqkv_kernel<2><<<1024, 256, 0, stream>>>(X, a, 256);
  }
  pma_attn_kernel<<<64, 256, 0, stream>>>(qpma, Kb, Vb, Opma);
  gemm_kernel<2, false><<<dim3(1, 4), 256, 0, stream>>>(Opma, (const float*)d_in[25],
      (const float*)d_in[26], Opma, O2, 64, 256, 256);
  gemm_kernel<1, false><<<dim3(1, 8), 256, 0, stream>>>(O2, (const float*)d_in[27],
      (const float*)d_in[28], nullptr, H1, 64, 512, 256);
  gemm_kernel<1, false><<<dim3(1, 8), 256, 0, stream>>>(H1, (const float*)d_in[29],
      (const float*)d_in[30], nullptr, H2, 64, 512, 512);
  gemm_kernel<0, true><<<dim3(1, 4), 256, 0, stream>>>(H2, (const float*)d_in[31],
      (const float*)d_in[32], nullptr, (float*)d_out, 64, 256, 512);
}